// Round 1
// baseline (1184.405 us; speedup 1.0000x reference)
//
#include <hip/hip_runtime.h>

constexpr int D_IN = 256, D_HID = 512, D_OUT = 48;
constexpr int K_STEPS = 10;

typedef __attribute__((ext_vector_type(8))) __bf16 bf16x8;
typedef __attribute__((ext_vector_type(4))) float f32x4;

__device__ __forceinline__ unsigned short f2bf(float f) {
  unsigned u = __builtin_bit_cast(unsigned, f);
  u += 0x7fffu + ((u >> 16) & 1u);   // round-to-nearest-even
  return (unsigned short)(u >> 16);
}

// ---------------- graph build ----------------

__global__ void zero2_kernel(int* __restrict__ a, int* __restrict__ b, int N) {
  int i = blockIdx.x * 256 + threadIdx.x;
  if (i < N) { a[i] = 0; b[i] = 0; }
}

__global__ void count_kernel(const int* __restrict__ dst, int* __restrict__ cnt, int E) {
  int e = blockIdx.x * 256 + threadIdx.x;
  if (e < E) atomicAdd(&cnt[dst[e]], 1);
}

__global__ void dinv_kernel(const int* __restrict__ cnt, float* __restrict__ dinv, int N) {
  int n = blockIdx.x * 256 + threadIdx.x;
  if (n < N) dinv[n] = rsqrtf((float)(cnt[n] + 1));  // +1 = self-loop
}

// exclusive scan of cnt -> row_ptr, two-level (1024 elems / block)
__global__ void scan1_kernel(const int* __restrict__ cnt, int* __restrict__ row_ptr,
                             int* __restrict__ bsum, int N) {
  __shared__ int sd[256];
  int tid = threadIdx.x, b = blockIdx.x;
  int i0 = b * 1024 + tid * 4;
  int v[4];
#pragma unroll
  for (int m = 0; m < 4; ++m) v[m] = (i0 + m < N) ? cnt[i0 + m] : 0;
  int s = v[0] + v[1] + v[2] + v[3];
  sd[tid] = s;
  __syncthreads();
  for (int off = 1; off < 256; off <<= 1) {
    int t = (tid >= off) ? sd[tid - off] : 0;
    __syncthreads();
    sd[tid] += t;
    __syncthreads();
  }
  int run = sd[tid] - s;  // exclusive prefix of this thread's chunk
#pragma unroll
  for (int m = 0; m < 4; ++m) {
    if (i0 + m < N) row_ptr[i0 + m] = run;
    run += v[m];
  }
  if (tid == 255) bsum[b] = sd[255];
}

__global__ void scan2_kernel(const int* __restrict__ bsum, int* __restrict__ bofs,
                             int* __restrict__ row_ptr, int NB, int N) {
  __shared__ int sd[128];
  int tid = threadIdx.x;
  int v = (tid < NB) ? bsum[tid] : 0;
  sd[tid] = v;
  __syncthreads();
  for (int off = 1; off < 128; off <<= 1) {
    int t = (tid >= off) ? sd[tid - off] : 0;
    __syncthreads();
    sd[tid] += t;
    __syncthreads();
  }
  if (tid < NB) bofs[tid] = sd[tid] - v;
  if (tid == 127) row_ptr[N] = sd[127];  // grand total = E
}

__global__ void scan3_kernel(int* __restrict__ row_ptr, const int* __restrict__ bofs, int N) {
  int b = blockIdx.x;
  if (b == 0) return;
  int add = bofs[b];
  int i0 = b * 1024 + threadIdx.x * 4;
#pragma unroll
  for (int m = 0; m < 4; ++m)
    if (i0 + m < N) row_ptr[i0 + m] += add;
}

__global__ void fill_kernel(const int* __restrict__ src, const int* __restrict__ dst,
                            const int* __restrict__ row_ptr, int* __restrict__ cnt2,
                            const float* __restrict__ dinv,
                            int* __restrict__ col, float* __restrict__ wv, int E) {
  int e = blockIdx.x * 256 + threadIdx.x;
  if (e >= E) return;
  int s = src[e], d = dst[e];
  int p = row_ptr[d] + atomicAdd(&cnt2[d], 1);
  col[p] = s;
  wv[p] = dinv[s];  // norm = dinv[src]*dinv[dst]; dinv[dst] applied per-node
}

// ---------------- weight convert ----------------

__global__ void convert_w1(const float* __restrict__ W1, unsigned short* __restrict__ W1T) {
  int i = blockIdx.x * 256 + threadIdx.x;  // W1T[c][k], c<512, k<256
  if (i >= D_HID * D_IN) return;
  int c = i >> 8, k = i & 255;
  W1T[i] = f2bf(W1[k * D_HID + c]);
}

__global__ void convert_w2(const float* __restrict__ W2, unsigned short* __restrict__ W2T) {
  int i = blockIdx.x * 256 + threadIdx.x;  // W2T[n][k], n<48, k<512
  if (i >= D_OUT * D_HID) return;
  int n = i >> 9, k = i & 511;
  W2T[i] = f2bf(W2[k * D_OUT + n]);
}

// ---------------- fused MLP encoder (bf16 MFMA) ----------------
// block: 256 threads (4 waves), 64 rows. hid computed in 64-col chunks,
// immediately consumed by GEMM2 so the [N,512] intermediate never exists.

__global__ __launch_bounds__(256, 2) void encoder_kernel(
    const float* __restrict__ x, const float* __restrict__ b1,
    const float* __restrict__ b2,
    const unsigned short* __restrict__ W1T,   // [512][256] bf16
    const unsigned short* __restrict__ W2T,   // [48][512]  bf16
    float* __restrict__ h, int N) {
  __shared__ unsigned short sX[64][264];   // rows x K, pad 8 (16B) -> 2-way max
  __shared__ unsigned short sB[64][72];    // W1T tile: n x k
  __shared__ unsigned short sHid[64][72];  // m x k(=hid col chunk)
  __shared__ unsigned short sW2[48][72];   // n x k

  int tid = threadIdx.x;
  int w = tid >> 6, lane = tid & 63;
  int q = lane >> 4, l15 = lane & 15;
  int row0 = blockIdx.x * 64;
  int m0 = w * 16;

  // stage sX: 64 rows x 256 fp32 -> bf16
#pragma unroll 4
  for (int i = 0; i < 16; ++i) {
    int idx = i * 256 + tid;  // float4 index, 64 per row
    int r = idx >> 6, c4 = idx & 63;
    int gr = row0 + r;
    float4 v = make_float4(0.f, 0.f, 0.f, 0.f);
    if (gr < N) v = *(const float4*)(x + (size_t)gr * D_IN + c4 * 4);
    unsigned short* p = &sX[r][c4 * 4];
    p[0] = f2bf(v.x); p[1] = f2bf(v.y); p[2] = f2bf(v.z); p[3] = f2bf(v.w);
  }

  f32x4 hacc[3];
#pragma unroll
  for (int t = 0; t < 3; ++t)
#pragma unroll
    for (int r = 0; r < 4; ++r) hacc[t][r] = 0.f;

  for (int ct = 0; ct < 8; ++ct) {
    int c0 = ct * 64;
    f32x4 acc[4];
#pragma unroll
    for (int t = 0; t < 4; ++t)
#pragma unroll
      for (int r = 0; r < 4; ++r) acc[t][r] = 0.f;

    for (int kt = 0; kt < 4; ++kt) {
      int k0 = kt * 64;
      __syncthreads();  // sB safe to overwrite (also covers initial sX stage)
#pragma unroll
      for (int i = 0; i < 2; ++i) {  // 64 rows x 4 uint4 chunks
        int id = i * 256 + tid;
        int r = id >> 3, c8 = id & 7;
        *(uint4*)&sB[r][c8 * 8] = *(const uint4*)(W1T + (size_t)(c0 + r) * D_IN + k0 + c8 * 8);
      }
      __syncthreads();
#pragma unroll
      for (int kk = 0; kk < 64; kk += 32) {
        bf16x8 a = *(const bf16x8*)&sX[m0 + l15][k0 + kk + q * 8];
#pragma unroll
        for (int tn = 0; tn < 4; ++tn) {
          bf16x8 b = *(const bf16x8*)&sB[tn * 16 + l15][kk + q * 8];
          acc[tn] = __builtin_amdgcn_mfma_f32_16x16x32_bf16(a, b, acc[tn], 0, 0, 0);
        }
      }
    }
    __syncthreads();  // prev ct's GEMM2 done reading sHid/sW2
    // relu(acc + b1) -> sHid (C/D layout: col=l15, row=q*4+rg)
#pragma unroll
    for (int tn = 0; tn < 4; ++tn) {
      int c = tn * 16 + l15;
      float bias = b1[c0 + c];
#pragma unroll
      for (int rg = 0; rg < 4; ++rg) {
        float v = acc[tn][rg] + bias;
        v = v > 0.f ? v : 0.f;
        sHid[m0 + q * 4 + rg][c] = f2bf(v);
      }
    }
    // stage sW2 tile: 48 x 64
#pragma unroll
    for (int i = 0; i < 2; ++i) {
      int id = i * 256 + tid;
      if (id < 384) {
        int r = id >> 3, c8 = id & 7;
        *(uint4*)&sW2[r][c8 * 8] = *(const uint4*)(W2T + (size_t)r * D_HID + c0 + c8 * 8);
      }
    }
    __syncthreads();
#pragma unroll
    for (int kk = 0; kk < 64; kk += 32) {
      bf16x8 a = *(const bf16x8*)&sHid[m0 + l15][kk + q * 8];
#pragma unroll
      for (int tn = 0; tn < 3; ++tn) {
        bf16x8 b = *(const bf16x8*)&sW2[tn * 16 + l15][kk + q * 8];
        hacc[tn] = __builtin_amdgcn_mfma_f32_16x16x32_bf16(a, b, hacc[tn], 0, 0, 0);
      }
    }
  }
  // epilogue: h = hacc + b2
#pragma unroll
  for (int tn = 0; tn < 3; ++tn) {
    int c = tn * 16 + l15;
    float bias = b2[c];
#pragma unroll
    for (int rg = 0; rg < 4; ++rg) {
      int gr = row0 + m0 + q * 4 + rg;
      if (gr < N) h[(size_t)gr * D_OUT + c] = hacc[tn][rg] + bias;
    }
  }
}

// ---------------- APPNP propagation: one wave per node ----------------

__global__ __launch_bounds__(256) void prop_kernel(
    const float* __restrict__ cur, const float* __restrict__ h,
    const float* __restrict__ dinv, const int* __restrict__ row_ptr,
    const int* __restrict__ col, const float* __restrict__ wv,
    float* __restrict__ nxt, int N) {
  int n = ((blockIdx.x * 256 + threadIdx.x) >> 6);  // wave id = node
  int lane = threadIdx.x & 63;
  if (n >= N) return;
  if (lane >= 48) return;
  int p0 = row_ptr[n], p1 = row_ptr[n + 1];
  float di = dinv[n];
  float acc = 0.f;
  int p = p0;
  for (; p + 4 <= p1; p += 4) {
    int s0 = col[p], s1 = col[p + 1], s2 = col[p + 2], s3 = col[p + 3];
    float w0 = wv[p], w1 = wv[p + 1], w2 = wv[p + 2], w3 = wv[p + 3];
    float g0 = cur[(size_t)s0 * 48 + lane];
    float g1 = cur[(size_t)s1 * 48 + lane];
    float g2 = cur[(size_t)s2 * 48 + lane];
    float g3 = cur[(size_t)s3 * 48 + lane];
    acc += w0 * g0; acc += w1 * g1; acc += w2 * g2; acc += w3 * g3;
  }
  for (; p < p1; ++p) {
    int s0 = col[p];
    acc += wv[p] * cur[(size_t)s0 * 48 + lane];
  }
  size_t base = (size_t)n * 48 + lane;
  float self = di * di * cur[base];          // self-loop edge
  float val = 0.9f * (di * acc + self) + 0.1f * h[base];
  nxt[base] = val;
}

// ---------------- launch ----------------

extern "C" void kernel_launch(void* const* d_in, const int* in_sizes, int n_in,
                              void* d_out, int out_size, void* d_ws, size_t ws_size,
                              hipStream_t stream) {
  (void)n_in; (void)out_size; (void)ws_size;
  const float* x  = (const float*)d_in[0];
  const int*   ei = (const int*)d_in[1];
  const float* W1 = (const float*)d_in[2];
  const float* b1 = (const float*)d_in[3];
  const float* W2 = (const float*)d_in[4];
  const float* b2 = (const float*)d_in[5];
  const int N = in_sizes[0] / D_IN;
  const int E = in_sizes[1] / 2;
  const int* e_src = ei;
  const int* e_dst = ei + E;

  char* ws = (char*)d_ws;
  size_t off = 0;
  auto take = [&](size_t bytes) -> char* {
    char* p = ws + off;
    off += (bytes + 511) & ~(size_t)511;
    return p;
  };
  int* cnt      = (int*)take((size_t)N * 4);
  int* cnt2     = (int*)take((size_t)N * 4);
  float* dinv   = (float*)take((size_t)N * 4);
  int* row_ptr  = (int*)take((size_t)(N + 1) * 4);
  int* bsum     = (int*)take(1024);
  int* bofs     = (int*)take(1024);
  int* col      = (int*)take((size_t)E * 4);
  float* wv     = (float*)take((size_t)E * 4);
  unsigned short* W1T = (unsigned short*)take((size_t)D_IN * D_HID * 2);
  unsigned short* W2T = (unsigned short*)take((size_t)D_HID * D_OUT * 2);
  float* hbuf   = (float*)take((size_t)N * D_OUT * 4);
  float* bufA   = (float*)take((size_t)N * D_OUT * 4);
  float* outp   = (float*)d_out;

  int nb256  = (N + 255) / 256;
  int eb256  = (E + 255) / 256;
  int NB     = (N + 1023) / 1024;   // <= 128 required (98 here)

  // graph build
  zero2_kernel<<<nb256, 256, 0, stream>>>(cnt, cnt2, N);
  count_kernel<<<eb256, 256, 0, stream>>>(e_dst, cnt, E);
  dinv_kernel<<<nb256, 256, 0, stream>>>(cnt, dinv, N);
  scan1_kernel<<<NB, 256, 0, stream>>>(cnt, row_ptr, bsum, N);
  scan2_kernel<<<1, 128, 0, stream>>>(bsum, bofs, row_ptr, NB, N);
  scan3_kernel<<<NB, 256, 0, stream>>>(row_ptr, bofs, N);
  fill_kernel<<<eb256, 256, 0, stream>>>(e_src, e_dst, row_ptr, cnt2, dinv, col, wv, E);

  // encoder
  convert_w1<<<(D_IN * D_HID + 255) / 256, 256, 0, stream>>>(W1, W1T);
  convert_w2<<<(D_HID * D_OUT + 255) / 256, 256, 0, stream>>>(W2, W2T);
  encoder_kernel<<<(N + 63) / 64, 256, 0, stream>>>(x, b1, b2, W1T, W2T, hbuf, N);

  // APPNP: h->A, A->out, out->A, ... , A->out (10 iters, ends in d_out)
  int pblocks = (N + 3) / 4;
  for (int it = 1; it <= K_STEPS; ++it) {
    const float* s = (it == 1) ? hbuf : ((it & 1) ? outp : bufA);
    float* d = (it & 1) ? bufA : outp;
    prop_kernel<<<pblocks, 256, 0, stream>>>(s, hbuf, dinv, row_ptr, col, wv, d, N);
  }
}

// Round 2
// 1032.678 us; speedup vs baseline: 1.1469x; 1.1469x over previous
//
#include <hip/hip_runtime.h>
#include <hip/hip_fp16.h>

constexpr int D_IN = 256, D_HID = 512, D_OUT = 48;
constexpr int K_STEPS = 10;

typedef __attribute__((ext_vector_type(8))) __bf16 bf16x8;
typedef __attribute__((ext_vector_type(4))) float f32x4;

__device__ __forceinline__ unsigned short f2bf(float f) {
  unsigned u = __builtin_bit_cast(unsigned, f);
  u += 0x7fffu + ((u >> 16) & 1u);   // round-to-nearest-even
  return (unsigned short)(u >> 16);
}

// ---------------- graph build ----------------

__global__ void zero2_kernel(int* __restrict__ a, int* __restrict__ b, int N) {
  int i = blockIdx.x * 256 + threadIdx.x;
  if (i < N) { a[i] = 0; b[i] = 0; }
}

__global__ void count_kernel(const int* __restrict__ dst, int* __restrict__ cnt, int E) {
  int e = blockIdx.x * 256 + threadIdx.x;
  if (e < E) atomicAdd(&cnt[dst[e]], 1);
}

__global__ void dinv_kernel(const int* __restrict__ cnt, float* __restrict__ dinv, int N) {
  int n = blockIdx.x * 256 + threadIdx.x;
  if (n < N) dinv[n] = rsqrtf((float)(cnt[n] + 1));  // +1 = self-loop
}

// exclusive scan of cnt -> row_ptr, two-level (1024 elems / block)
__global__ void scan1_kernel(const int* __restrict__ cnt, int* __restrict__ row_ptr,
                             int* __restrict__ bsum, int N) {
  __shared__ int sd[256];
  int tid = threadIdx.x, b = blockIdx.x;
  int i0 = b * 1024 + tid * 4;
  int v[4];
#pragma unroll
  for (int m = 0; m < 4; ++m) v[m] = (i0 + m < N) ? cnt[i0 + m] : 0;
  int s = v[0] + v[1] + v[2] + v[3];
  sd[tid] = s;
  __syncthreads();
  for (int off = 1; off < 256; off <<= 1) {
    int t = (tid >= off) ? sd[tid - off] : 0;
    __syncthreads();
    sd[tid] += t;
    __syncthreads();
  }
  int run = sd[tid] - s;
#pragma unroll
  for (int m = 0; m < 4; ++m) {
    if (i0 + m < N) row_ptr[i0 + m] = run;
    run += v[m];
  }
  if (tid == 255) bsum[b] = sd[255];
}

__global__ void scan2_kernel(const int* __restrict__ bsum, int* __restrict__ bofs,
                             int* __restrict__ row_ptr, int NB, int N) {
  __shared__ int sd[128];
  int tid = threadIdx.x;
  int v = (tid < NB) ? bsum[tid] : 0;
  sd[tid] = v;
  __syncthreads();
  for (int off = 1; off < 128; off <<= 1) {
    int t = (tid >= off) ? sd[tid - off] : 0;
    __syncthreads();
    sd[tid] += t;
    __syncthreads();
  }
  if (tid < NB) bofs[tid] = sd[tid] - v;
  if (tid == 127) row_ptr[N] = sd[127];
}

__global__ void scan3_kernel(int* __restrict__ row_ptr, const int* __restrict__ bofs, int N) {
  int b = blockIdx.x;
  if (b == 0) return;
  int add = bofs[b];
  int i0 = b * 1024 + threadIdx.x * 4;
#pragma unroll
  for (int m = 0; m < 4; ++m)
    if (i0 + m < N) row_ptr[i0 + m] += add;
}

// edges[p] = {src, dinv[src] bits}
__global__ void fill_kernel(const int* __restrict__ src, const int* __restrict__ dst,
                            const int* __restrict__ row_ptr, int* __restrict__ cnt2,
                            const float* __restrict__ dinv,
                            int2* __restrict__ edges, int E) {
  int e = blockIdx.x * 256 + threadIdx.x;
  if (e >= E) return;
  int s = src[e], d = dst[e];
  int p = row_ptr[d] + atomicAdd(&cnt2[d], 1);
  edges[p] = make_int2(s, __float_as_int(dinv[s]));
}

// ---------------- weight convert ----------------

__global__ void convert_w1(const float* __restrict__ W1, unsigned short* __restrict__ W1T) {
  int i = blockIdx.x * 256 + threadIdx.x;  // W1T[c][k], c<512, k<256
  if (i >= D_HID * D_IN) return;
  int c = i >> 8, k = i & 255;
  W1T[i] = f2bf(W1[k * D_HID + c]);
}

__global__ void convert_w2(const float* __restrict__ W2, unsigned short* __restrict__ W2T) {
  int i = blockIdx.x * 256 + threadIdx.x;  // W2T[n][k], n<48, k<512
  if (i >= D_OUT * D_HID) return;
  int n = i >> 9, k = i & 511;
  W2T[i] = f2bf(W2[k * D_OUT + n]);
}

// ---------------- fused MLP encoder (bf16 MFMA, A-frags in registers) ----------------
// 256 threads / 64 rows per block. x fragments live in 32 VGPRs/lane for the
// whole kernel (no sX). Output h written directly as f16.

__global__ __launch_bounds__(256, 3) void encoder_kernel(
    const float* __restrict__ x, const float* __restrict__ b1,
    const float* __restrict__ b2,
    const unsigned short* __restrict__ W1T,   // [512][256] bf16
    const unsigned short* __restrict__ W2T,   // [48][512]  bf16
    __half* __restrict__ h2, int N) {
  __shared__ unsigned short sB[64][264];    // W1T ct-tile: c(64) x k(256), pad 8
  __shared__ unsigned short sHid[64][72];   // m x hid-col(64)
  __shared__ unsigned short sW2[48][72];    // n(48) x hid-col(64)

  int tid = threadIdx.x;
  int w = tid >> 6, lane = tid & 63;
  int q = lane >> 4, l15 = lane & 15;
  int row0 = blockIdx.x * 64;
  int m0 = w * 16;

  // A fragments: 16 rows per wave, k = 0..255. axf[jb] covers k in [jb*32, jb*32+32)
  bf16x8 axf[8];
  {
    int grow = row0 + m0 + l15;
    bool rok = grow < N;
    const float* xr = x + (size_t)grow * D_IN;
#pragma unroll
    for (int jb = 0; jb < 8; ++jb) {
      float4 v0 = make_float4(0.f, 0.f, 0.f, 0.f), v1 = v0;
      if (rok) {
        v0 = *(const float4*)(xr + jb * 32 + q * 8);
        v1 = *(const float4*)(xr + jb * 32 + q * 8 + 4);
      }
      union { bf16x8 v; unsigned short s[8]; } u;
      u.s[0] = f2bf(v0.x); u.s[1] = f2bf(v0.y); u.s[2] = f2bf(v0.z); u.s[3] = f2bf(v0.w);
      u.s[4] = f2bf(v1.x); u.s[5] = f2bf(v1.y); u.s[6] = f2bf(v1.z); u.s[7] = f2bf(v1.w);
      axf[jb] = u.v;
    }
  }

  f32x4 hacc[3];
#pragma unroll
  for (int t = 0; t < 3; ++t)
#pragma unroll
    for (int r = 0; r < 4; ++r) hacc[t][r] = 0.f;

  for (int ct = 0; ct < 8; ++ct) {
    int c0 = ct * 64;
    __syncthreads();  // prev GEMM2 done with sHid/sW2; sB free
    // stage sB: 64 rows x 32 uint4
#pragma unroll
    for (int i = 0; i < 8; ++i) {
      int id = i * 256 + tid;
      int r = id >> 5, c = id & 31;
      *(uint4*)&sB[r][c * 8] = *(const uint4*)(W1T + (size_t)(c0 + r) * D_IN + c * 8);
    }
    // stage sW2: 48 rows x 8 uint4
    {
      int id = tid;
      if (id < 384) {
        int r = id >> 3, c8 = id & 7;
        *(uint4*)&sW2[r][c8 * 8] = *(const uint4*)(W2T + (size_t)r * D_HID + c0 + c8 * 8);
      }
      id = 256 + tid;
      if (id < 384) {
        int r = id >> 3, c8 = id & 7;
        *(uint4*)&sW2[r][c8 * 8] = *(const uint4*)(W2T + (size_t)r * D_HID + c0 + c8 * 8);
      }
    }
    __syncthreads();

    f32x4 acc[4];
#pragma unroll
    for (int t = 0; t < 4; ++t)
#pragma unroll
      for (int r = 0; r < 4; ++r) acc[t][r] = 0.f;
#pragma unroll
    for (int kb = 0; kb < 8; ++kb) {
      bf16x8 a = axf[kb];
#pragma unroll
      for (int tn = 0; tn < 4; ++tn) {
        bf16x8 b = *(const bf16x8*)&sB[tn * 16 + l15][kb * 32 + q * 8];
        acc[tn] = __builtin_amdgcn_mfma_f32_16x16x32_bf16(a, b, acc[tn], 0, 0, 0);
      }
    }
    __syncthreads();
    // relu(acc + b1) -> sHid (C/D layout: col=l15, row=q*4+rg)
#pragma unroll
    for (int tn = 0; tn < 4; ++tn) {
      int c = tn * 16 + l15;
      float bias = b1[c0 + c];
#pragma unroll
      for (int rg = 0; rg < 4; ++rg) {
        float v = acc[tn][rg] + bias;
        v = v > 0.f ? v : 0.f;
        sHid[m0 + q * 4 + rg][c] = f2bf(v);
      }
    }
    __syncthreads();
#pragma unroll
    for (int kk = 0; kk < 2; ++kk) {
      bf16x8 a = *(const bf16x8*)&sHid[m0 + l15][kk * 32 + q * 8];
#pragma unroll
      for (int tn = 0; tn < 3; ++tn) {
        bf16x8 b = *(const bf16x8*)&sW2[tn * 16 + l15][kk * 32 + q * 8];
        hacc[tn] = __builtin_amdgcn_mfma_f32_16x16x32_bf16(a, b, hacc[tn], 0, 0, 0);
      }
    }
  }
  // epilogue: h2 = f16(hacc + b2)
#pragma unroll
  for (int tn = 0; tn < 3; ++tn) {
    int c = tn * 16 + l15;
    float bias = b2[c];
#pragma unroll
    for (int rg = 0; rg < 4; ++rg) {
      int gr = row0 + m0 + q * 4 + rg;
      if (gr < N) h2[(size_t)gr * D_OUT + c] = __float2half(hacc[tn][rg] + bias);
    }
  }
}

// ---------------- APPNP propagation: f16 state, 2 edges per gather ----------------
// wave = node. lanes 0..23 = edge slot 0, lanes 24..47 = edge slot 1;
// each lane covers a feature PAIR (f16x2). One gather instruction serves 2 edges.

__global__ __launch_bounds__(256) void prop_kernel(
    const __half* __restrict__ cur, const __half* __restrict__ h2,
    const float* __restrict__ dinv, const int* __restrict__ row_ptr,
    const int2* __restrict__ edges, __half* __restrict__ nxt,
    float* __restrict__ outf, int N, int last) {
  int n = (blockIdx.x * 256 + threadIdx.x) >> 6;
  int lane = threadIdx.x & 63;
  if (n >= N || lane >= 48) return;
  int g = (lane >= 24) ? 1 : 0;   // edge slot
  int j = lane - g * 24;          // feature-pair index 0..23
  int p0 = row_ptr[n], p1 = row_ptr[n + 1];
  float di = dinv[n];
  float ax = 0.f, ay = 0.f;
  int p = p0;
#pragma unroll 2
  for (; p + 2 <= p1; p += 2) {
    int2 e = edges[p + g];
    float wgt = __int_as_float(e.y);
    __half2 hv = *(const __half2*)(cur + (size_t)e.x * 48 + j * 2);
    float2 f = __half22float2(hv);
    ax += wgt * f.x; ay += wgt * f.y;
  }
  if (p < p1 && g == 0) {  // odd tail: slot-0 lanes only
    int2 e = edges[p];
    float wgt = __int_as_float(e.y);
    __half2 hv = *(const __half2*)(cur + (size_t)e.x * 48 + j * 2);
    float2 f = __half22float2(hv);
    ax += wgt * f.x; ay += wgt * f.y;
  }
  // combine slots: lanes 0..23 pull lane+24's partials
  ax += __shfl(ax, lane + 24);
  ay += __shfl(ay, lane + 24);
  if (lane >= 24) return;
  size_t base = (size_t)n * 48 + j * 2;
  float2 self = __half22float2(*(const __half2*)(cur + base));
  float2 hp = __half22float2(*(const __half2*)(h2 + base));
  float dii = di * di;
  float vx = 0.9f * (di * ax + dii * self.x) + 0.1f * hp.x;
  float vy = 0.9f * (di * ay + dii * self.y) + 0.1f * hp.y;
  if (last) {
    *(float2*)(outf + base) = make_float2(vx, vy);
  } else {
    *(__half2*)(nxt + base) = __floats2half2_rn(vx, vy);
  }
}

// ---------------- launch ----------------

extern "C" void kernel_launch(void* const* d_in, const int* in_sizes, int n_in,
                              void* d_out, int out_size, void* d_ws, size_t ws_size,
                              hipStream_t stream) {
  (void)n_in; (void)out_size; (void)ws_size;
  const float* x  = (const float*)d_in[0];
  const int*   ei = (const int*)d_in[1];
  const float* W1 = (const float*)d_in[2];
  const float* b1 = (const float*)d_in[3];
  const float* W2 = (const float*)d_in[4];
  const float* b2 = (const float*)d_in[5];
  const int N = in_sizes[0] / D_IN;
  const int E = in_sizes[1] / 2;
  const int* e_src = ei;
  const int* e_dst = ei + E;

  char* ws = (char*)d_ws;
  size_t off = 0;
  auto take = [&](size_t bytes) -> char* {
    char* p = ws + off;
    off += (bytes + 511) & ~(size_t)511;
    return p;
  };
  int* cnt      = (int*)take((size_t)N * 4);
  int* cnt2     = (int*)take((size_t)N * 4);
  float* dinv   = (float*)take((size_t)N * 4);
  int* row_ptr  = (int*)take((size_t)(N + 1) * 4);
  int* bsum     = (int*)take(1024);
  int* bofs     = (int*)take(1024);
  int2* edges   = (int2*)take((size_t)E * 8);
  unsigned short* W1T = (unsigned short*)take((size_t)D_IN * D_HID * 2);
  unsigned short* W2T = (unsigned short*)take((size_t)D_HID * D_OUT * 2);
  __half* h2    = (__half*)take((size_t)N * D_OUT * 2);
  __half* bufA  = (__half*)take((size_t)N * D_OUT * 2);
  __half* bufB  = (__half*)take((size_t)N * D_OUT * 2);
  float* outp   = (float*)d_out;

  int nb256 = (N + 255) / 256;
  int eb256 = (E + 255) / 256;
  int NB    = (N + 1023) / 1024;   // 98 <= 128 ok

  // graph build
  zero2_kernel<<<nb256, 256, 0, stream>>>(cnt, cnt2, N);
  count_kernel<<<eb256, 256, 0, stream>>>(e_dst, cnt, E);
  dinv_kernel<<<nb256, 256, 0, stream>>>(cnt, dinv, N);
  scan1_kernel<<<NB, 256, 0, stream>>>(cnt, row_ptr, bsum, N);
  scan2_kernel<<<1, 128, 0, stream>>>(bsum, bofs, row_ptr, NB, N);
  scan3_kernel<<<NB, 256, 0, stream>>>(row_ptr, bofs, N);
  fill_kernel<<<eb256, 256, 0, stream>>>(e_src, e_dst, row_ptr, cnt2, dinv, edges, E);

  // encoder
  convert_w1<<<(D_IN * D_HID + 255) / 256, 256, 0, stream>>>(W1, W1T);
  convert_w2<<<(D_HID * D_OUT + 255) / 256, 256, 0, stream>>>(W2, W2T);
  encoder_kernel<<<(N + 63) / 64, 256, 0, stream>>>(x, b1, b2, W1T, W2T, h2, N);

  // APPNP: 10 iters; last writes f32 d_out
  int pblocks = (N + 3) / 4;
  const __half* src = h2;
  __half* dst = bufA;
  for (int it = 1; it <= K_STEPS; ++it) {
    int last = (it == K_STEPS);
    prop_kernel<<<pblocks, 256, 0, stream>>>(src, h2, dinv, row_ptr, edges,
                                             dst, outp, N, last);
    src = dst;
    dst = (dst == bufA) ? bufB : bufA;
  }
}

// Round 3
// 840.951 us; speedup vs baseline: 1.4084x; 1.2280x over previous
//
#include <hip/hip_runtime.h>
#include <hip/hip_fp16.h>

constexpr int D_IN = 256, D_HID = 512, D_OUT = 48;
constexpr int K_STEPS = 10;

typedef __attribute__((ext_vector_type(8))) __bf16 bf16x8;
typedef __attribute__((ext_vector_type(4))) float f32x4;

__device__ __forceinline__ unsigned short f2bf(float f) {
  unsigned u = __builtin_bit_cast(unsigned, f);
  u += 0x7fffu + ((u >> 16) & 1u);   // round-to-nearest-even
  return (unsigned short)(u >> 16);
}

// ---------------- graph build ----------------

__global__ void zero2_kernel(int* __restrict__ a, int* __restrict__ b, int N) {
  int i = blockIdx.x * 256 + threadIdx.x;
  if (i < N) { a[i] = 0; b[i] = 0; }
}

__global__ void count_kernel(const int* __restrict__ dst, int* __restrict__ cnt, int E) {
  int e = blockIdx.x * 256 + threadIdx.x;
  if (e < E) atomicAdd(&cnt[dst[e]], 1);
}

__global__ void dinv_kernel(const int* __restrict__ cnt, float* __restrict__ dinv, int N) {
  int n = blockIdx.x * 256 + threadIdx.x;
  if (n < N) dinv[n] = rsqrtf((float)(cnt[n] + 1));  // +1 = self-loop
}

// exclusive scan of cnt -> row_ptr, two-level (1024 elems / block)
__global__ void scan1_kernel(const int* __restrict__ cnt, int* __restrict__ row_ptr,
                             int* __restrict__ bsum, int N) {
  __shared__ int sd[256];
  int tid = threadIdx.x, b = blockIdx.x;
  int i0 = b * 1024 + tid * 4;
  int v[4];
#pragma unroll
  for (int m = 0; m < 4; ++m) v[m] = (i0 + m < N) ? cnt[i0 + m] : 0;
  int s = v[0] + v[1] + v[2] + v[3];
  sd[tid] = s;
  __syncthreads();
  for (int off = 1; off < 256; off <<= 1) {
    int t = (tid >= off) ? sd[tid - off] : 0;
    __syncthreads();
    sd[tid] += t;
    __syncthreads();
  }
  int run = sd[tid] - s;
#pragma unroll
  for (int m = 0; m < 4; ++m) {
    if (i0 + m < N) row_ptr[i0 + m] = run;
    run += v[m];
  }
  if (tid == 255) bsum[b] = sd[255];
}

__global__ void scan2_kernel(const int* __restrict__ bsum, int* __restrict__ bofs,
                             int* __restrict__ row_ptr, int NB, int N) {
  __shared__ int sd[128];
  int tid = threadIdx.x;
  int v = (tid < NB) ? bsum[tid] : 0;
  sd[tid] = v;
  __syncthreads();
  for (int off = 1; off < 128; off <<= 1) {
    int t = (tid >= off) ? sd[tid - off] : 0;
    __syncthreads();
    sd[tid] += t;
    __syncthreads();
  }
  if (tid < NB) bofs[tid] = sd[tid] - v;
  if (tid == 127) row_ptr[N] = sd[127];
}

__global__ void scan3_kernel(int* __restrict__ row_ptr, const int* __restrict__ bofs, int N) {
  int b = blockIdx.x;
  if (b == 0) return;
  int add = bofs[b];
  int i0 = b * 1024 + threadIdx.x * 4;
#pragma unroll
  for (int m = 0; m < 4; ++m)
    if (i0 + m < N) row_ptr[i0 + m] += add;
}

// edges[p] = {src, dinv[src] bits}
__global__ void fill_kernel(const int* __restrict__ src, const int* __restrict__ dst,
                            const int* __restrict__ row_ptr, int* __restrict__ cnt2,
                            const float* __restrict__ dinv,
                            int2* __restrict__ edges, int E) {
  int e = blockIdx.x * 256 + threadIdx.x;
  if (e >= E) return;
  int s = src[e], d = dst[e];
  int p = row_ptr[d] + atomicAdd(&cnt2[d], 1);
  edges[p] = make_int2(s, __float_as_int(dinv[s]));
}

// ---------------- weight convert ----------------

__global__ void convert_w1(const float* __restrict__ W1, unsigned short* __restrict__ W1T) {
  int i = blockIdx.x * 256 + threadIdx.x;  // W1T[c][k], c<512, k<256
  if (i >= D_HID * D_IN) return;
  int c = i >> 8, k = i & 255;
  W1T[i] = f2bf(W1[k * D_HID + c]);
}

__global__ void convert_w2(const float* __restrict__ W2, unsigned short* __restrict__ W2T) {
  int i = blockIdx.x * 256 + threadIdx.x;  // W2T[n][k], n<48, k<512
  if (i >= D_OUT * D_HID) return;
  int n = i >> 9, k = i & 511;
  W2T[i] = f2bf(W2[k * D_OUT + n]);
}

// ---------------- fused MLP encoder ----------------
// 128 rows / block, 4 waves. Each wave: 2 row-tiles (A-frags in regs), so one
// sB ds_read_b128 feeds 2 MFMAs. sB staged in 128-k halves -> LDS 42.7 KB,
// 3 blocks/CU. sHid is wave-private: no __syncthreads around the transpose.

__global__ __launch_bounds__(256, 3) void encoder_kernel(
    const float* __restrict__ x, const float* __restrict__ b1,
    const float* __restrict__ b2,
    const unsigned short* __restrict__ W1T,   // [512][256] bf16
    const unsigned short* __restrict__ W2T,   // [48][512]  bf16
    __half* __restrict__ h2, int N) {
  __shared__ unsigned short sB[64][136];    // W1T tile: c(64) x k(128), pad 8
  __shared__ unsigned short sHid[128][72];  // m x hid-col(64), wave-private rows
  __shared__ unsigned short sW2[48][72];    // n(48) x hid-col(64)

  int tid = threadIdx.x;
  int w = tid >> 6, lane = tid & 63;
  int q = lane >> 4, l15 = lane & 15;
  int row0 = blockIdx.x * 128;
  int m0 = w * 16;

  // A fragments: 2 tiles x 16 rows, k = 0..255 (64 VGPRs)
  bf16x8 axf[2][8];
#pragma unroll
  for (int mt = 0; mt < 2; ++mt) {
    int grow = row0 + mt * 64 + m0 + l15;
    bool rok = grow < N;
    const float* xr = x + (size_t)grow * D_IN;
#pragma unroll
    for (int jb = 0; jb < 8; ++jb) {
      float4 v0 = make_float4(0.f, 0.f, 0.f, 0.f), v1 = v0;
      if (rok) {
        v0 = *(const float4*)(xr + jb * 32 + q * 8);
        v1 = *(const float4*)(xr + jb * 32 + q * 8 + 4);
      }
      union { bf16x8 v; unsigned short s[8]; } u;
      u.s[0] = f2bf(v0.x); u.s[1] = f2bf(v0.y); u.s[2] = f2bf(v0.z); u.s[3] = f2bf(v0.w);
      u.s[4] = f2bf(v1.x); u.s[5] = f2bf(v1.y); u.s[6] = f2bf(v1.z); u.s[7] = f2bf(v1.w);
      axf[mt][jb] = u.v;
    }
  }

  f32x4 hacc[2][3];
#pragma unroll
  for (int mt = 0; mt < 2; ++mt)
#pragma unroll
    for (int t = 0; t < 3; ++t)
#pragma unroll
      for (int r = 0; r < 4; ++r) hacc[mt][t][r] = 0.f;

  for (int ct = 0; ct < 8; ++ct) {
    int c0 = ct * 64;
    f32x4 acc[2][4];
#pragma unroll
    for (int mt = 0; mt < 2; ++mt)
#pragma unroll
      for (int t = 0; t < 4; ++t)
#pragma unroll
        for (int r = 0; r < 4; ++r) acc[mt][t][r] = 0.f;

#pragma unroll
    for (int kh = 0; kh < 2; ++kh) {
      __syncthreads();  // all waves done reading prev sB (and prev-ct sW2)
      // stage sB k-half: 64 rows x 16 uint4 = 1024; 4 per thread
#pragma unroll
      for (int i = 0; i < 4; ++i) {
        int id = i * 256 + tid;
        int r = id >> 4, c = id & 15;
        *(uint4*)&sB[r][c * 8] =
            *(const uint4*)(W1T + (size_t)(c0 + r) * D_IN + kh * 128 + c * 8);
      }
      if (kh == 0) {
        // stage sW2: 48 rows x 8 uint4 = 384
        int r = tid >> 3, c8 = tid & 7;
        *(uint4*)&sW2[r][c8 * 8] = *(const uint4*)(W2T + (size_t)r * D_HID + c0 + c8 * 8);
        int id = 256 + tid;
        if (id < 384) {
          int r2 = id >> 3, c2 = id & 7;
          *(uint4*)&sW2[r2][c2 * 8] = *(const uint4*)(W2T + (size_t)r2 * D_HID + c0 + c2 * 8);
        }
      }
      __syncthreads();
#pragma unroll
      for (int kb = 0; kb < 4; ++kb) {
#pragma unroll
        for (int tn = 0; tn < 4; ++tn) {
          bf16x8 b = *(const bf16x8*)&sB[tn * 16 + l15][kb * 32 + q * 8];
          acc[0][tn] = __builtin_amdgcn_mfma_f32_16x16x32_bf16(axf[0][kh * 4 + kb], b, acc[0][tn], 0, 0, 0);
          acc[1][tn] = __builtin_amdgcn_mfma_f32_16x16x32_bf16(axf[1][kh * 4 + kb], b, acc[1][tn], 0, 0, 0);
        }
      }
    }
    // relu(acc + b1) -> sHid (wave-private rows; compiler's lgkmcnt covers RAW)
#pragma unroll
    for (int mt = 0; mt < 2; ++mt)
#pragma unroll
      for (int tn = 0; tn < 4; ++tn) {
        int c = tn * 16 + l15;
        float bias = b1[c0 + c];
#pragma unroll
        for (int rg = 0; rg < 4; ++rg) {
          float v = acc[mt][tn][rg] + bias;
          v = v > 0.f ? v : 0.f;
          sHid[mt * 64 + m0 + q * 4 + rg][c] = f2bf(v);
        }
      }
#pragma unroll
    for (int kk = 0; kk < 2; ++kk) {
      bf16x8 a0 = *(const bf16x8*)&sHid[m0 + l15][kk * 32 + q * 8];
      bf16x8 a1 = *(const bf16x8*)&sHid[64 + m0 + l15][kk * 32 + q * 8];
#pragma unroll
      for (int tn = 0; tn < 3; ++tn) {
        bf16x8 b = *(const bf16x8*)&sW2[tn * 16 + l15][kk * 32 + q * 8];
        hacc[0][tn] = __builtin_amdgcn_mfma_f32_16x16x32_bf16(a0, b, hacc[0][tn], 0, 0, 0);
        hacc[1][tn] = __builtin_amdgcn_mfma_f32_16x16x32_bf16(a1, b, hacc[1][tn], 0, 0, 0);
      }
    }
  }
  // epilogue: h2 = f16(hacc + b2)
#pragma unroll
  for (int mt = 0; mt < 2; ++mt)
#pragma unroll
    for (int tn = 0; tn < 3; ++tn) {
      int c = tn * 16 + l15;
      float bias = b2[c];
#pragma unroll
      for (int rg = 0; rg < 4; ++rg) {
        int gr = row0 + mt * 64 + m0 + q * 4 + rg;
        if (gr < N) h2[(size_t)gr * D_OUT + c] = __float2half(hacc[mt][tn][rg] + bias);
      }
    }
}

// ---------------- APPNP propagation: 8 edges per gather ----------------
// wave = node. 48 lanes = 8 edge-slots x 6 lanes; each lane loads 16 B
// (8 f16 features) of its slot's source row. Edge records prefetched one
// batch ahead. 3-shuffle reduction once per node.

__global__ __launch_bounds__(256) void prop_kernel(
    const __half* __restrict__ cur, const __half* __restrict__ h2,
    const float* __restrict__ dinv, const int* __restrict__ row_ptr,
    const int2* __restrict__ edges, __half* __restrict__ nxt,
    float* __restrict__ outf, int N, int last) {
  int n = (blockIdx.x * 256 + threadIdx.x) >> 6;
  int lane = threadIdx.x & 63;
  if (n >= N || lane >= 48) return;
  int g = lane / 6;        // edge slot 0..7
  int s = lane - g * 6;    // 16-B feature chunk 0..5 (features s*8 .. s*8+7)
  int2 pp = *(const int2*)(row_ptr + n);
  int p0 = pp.x, p1 = pp.y;
  float di = dinv[n];
  float acc[8];
#pragma unroll
  for (int i = 0; i < 8; ++i) acc[i] = 0.f;

  int nb = (p1 - p0 + 7) >> 3;  // batches of 8 edges
  int p = p0 + g;
  int2 er = make_int2(0, 0);
  if (nb > 0) er = edges[min(p, p1 - 1)];
  for (int b = 0; b < nb; ++b) {
    float wgt = (p < p1) ? __int_as_float(er.y) : 0.f;
    int sn = er.x;
    int pn = p + 8;
    int2 ern = er;
    if (b + 1 < nb) ern = edges[min(pn, p1 - 1)];  // prefetch next records
    union { float4 f; __half2 h[4]; } u;
    u.f = *(const float4*)(cur + (size_t)sn * 48 + s * 8);
#pragma unroll
    for (int i = 0; i < 4; ++i) {
      float2 f = __half22float2(u.h[i]);
      acc[2 * i]     += wgt * f.x;
      acc[2 * i + 1] += wgt * f.y;
    }
    er = ern; p = pn;
  }
  // reduce the 8 edge slots into slot 0 (lanes 0..5)
#pragma unroll
  for (int off = 24; off >= 6; off >>= 1) {
#pragma unroll
    for (int i = 0; i < 8; ++i) acc[i] += __shfl(acc[i], lane + off);
  }
  if (lane >= 6) return;
  size_t base = (size_t)n * 48 + s * 8;
  union { float4 f; __half2 h[4]; } us, uh;
  us.f = *(const float4*)(cur + base);
  uh.f = *(const float4*)(h2 + base);
  float dii = di * di;
  float outv[8];
#pragma unroll
  for (int i = 0; i < 4; ++i) {
    float2 sf = __half22float2(us.h[i]);
    float2 hf = __half22float2(uh.h[i]);
    outv[2 * i]     = 0.9f * (di * acc[2 * i]     + dii * sf.x) + 0.1f * hf.x;
    outv[2 * i + 1] = 0.9f * (di * acc[2 * i + 1] + dii * sf.y) + 0.1f * hf.y;
  }
  if (last) {
    *(float4*)(outf + base)     = make_float4(outv[0], outv[1], outv[2], outv[3]);
    *(float4*)(outf + base + 4) = make_float4(outv[4], outv[5], outv[6], outv[7]);
  } else {
    union { uint4 u4; __half2 h[4]; } o;
#pragma unroll
    for (int i = 0; i < 4; ++i) o.h[i] = __floats2half2_rn(outv[2 * i], outv[2 * i + 1]);
    *(uint4*)(nxt + base) = o.u4;
  }
}

// ---------------- launch ----------------

extern "C" void kernel_launch(void* const* d_in, const int* in_sizes, int n_in,
                              void* d_out, int out_size, void* d_ws, size_t ws_size,
                              hipStream_t stream) {
  (void)n_in; (void)out_size; (void)ws_size;
  const float* x  = (const float*)d_in[0];
  const int*   ei = (const int*)d_in[1];
  const float* W1 = (const float*)d_in[2];
  const float* b1 = (const float*)d_in[3];
  const float* W2 = (const float*)d_in[4];
  const float* b2 = (const float*)d_in[5];
  const int N = in_sizes[0] / D_IN;
  const int E = in_sizes[1] / 2;
  const int* e_src = ei;
  const int* e_dst = ei + E;

  char* ws = (char*)d_ws;
  size_t off = 0;
  auto take = [&](size_t bytes) -> char* {
    char* p = ws + off;
    off += (bytes + 511) & ~(size_t)511;
    return p;
  };
  int* cnt      = (int*)take((size_t)N * 4);
  int* cnt2     = (int*)take((size_t)N * 4);
  float* dinv   = (float*)take((size_t)N * 4);
  int* row_ptr  = (int*)take((size_t)(N + 1) * 4);
  int* bsum     = (int*)take(1024);
  int* bofs     = (int*)take(1024);
  int2* edges   = (int2*)take((size_t)E * 8);
  unsigned short* W1T = (unsigned short*)take((size_t)D_IN * D_HID * 2);
  unsigned short* W2T = (unsigned short*)take((size_t)D_HID * D_OUT * 2);
  __half* h2    = (__half*)take((size_t)N * D_OUT * 2);
  __half* bufA  = (__half*)take((size_t)N * D_OUT * 2);
  __half* bufB  = (__half*)take((size_t)N * D_OUT * 2);
  float* outp   = (float*)d_out;

  int nb256 = (N + 255) / 256;
  int eb256 = (E + 255) / 256;
  int NB    = (N + 1023) / 1024;   // 98 <= 128 ok

  // graph build
  zero2_kernel<<<nb256, 256, 0, stream>>>(cnt, cnt2, N);
  count_kernel<<<eb256, 256, 0, stream>>>(e_dst, cnt, E);
  dinv_kernel<<<nb256, 256, 0, stream>>>(cnt, dinv, N);
  scan1_kernel<<<NB, 256, 0, stream>>>(cnt, row_ptr, bsum, N);
  scan2_kernel<<<1, 128, 0, stream>>>(bsum, bofs, row_ptr, NB, N);
  scan3_kernel<<<NB, 256, 0, stream>>>(row_ptr, bofs, N);
  fill_kernel<<<eb256, 256, 0, stream>>>(e_src, e_dst, row_ptr, cnt2, dinv, edges, E);

  // encoder
  convert_w1<<<(D_IN * D_HID + 255) / 256, 256, 0, stream>>>(W1, W1T);
  convert_w2<<<(D_HID * D_OUT + 255) / 256, 256, 0, stream>>>(W2, W2T);
  encoder_kernel<<<(N + 127) / 128, 256, 0, stream>>>(x, b1, b2, W1T, W2T, h2, N);

  // APPNP: 10 iters; last writes f32 d_out
  int pblocks = (N + 3) / 4;
  const __half* src = h2;
  __half* dst = bufA;
  for (int it = 1; it <= K_STEPS; ++it) {
    int last = (it == K_STEPS);
    prop_kernel<<<pblocks, 256, 0, stream>>>(src, h2, dinv, row_ptr, edges,
                                             dst, outp, N, last);
    src = dst;
    dst = (dst == bufA) ? bufB : bufA;
  }
}

// Round 4
// 748.965 us; speedup vs baseline: 1.5814x; 1.1228x over previous
//
#include <hip/hip_runtime.h>
#include <hip/hip_fp16.h>

constexpr int D_IN = 256, D_HID = 512, D_OUT = 48;
constexpr int HPAD = 64;   // padded feature stride (f16) -> 128 B rows
constexpr int K_STEPS = 10;

typedef __attribute__((ext_vector_type(8))) __bf16 bf16x8;
typedef __attribute__((ext_vector_type(4))) float f32x4;

__device__ __forceinline__ unsigned short f2bf(float f) {
  unsigned u = __builtin_bit_cast(unsigned, f);
  u += 0x7fffu + ((u >> 16) & 1u);   // round-to-nearest-even
  return (unsigned short)(u >> 16);
}

// ---------------- graph build ----------------

__global__ void zero2_kernel(int* __restrict__ a, int* __restrict__ b, int N) {
  int i = blockIdx.x * 256 + threadIdx.x;
  if (i < N) { a[i] = 0; b[i] = 0; }
}

__global__ void count_kernel(const int* __restrict__ dst, int* __restrict__ cnt, int E) {
  int e = blockIdx.x * 256 + threadIdx.x;
  if (e < E) atomicAdd(&cnt[dst[e]], 1);
}

__global__ void dinv_kernel(const int* __restrict__ cnt, float* __restrict__ dinv, int N) {
  int n = blockIdx.x * 256 + threadIdx.x;
  if (n < N) dinv[n] = rsqrtf((float)(cnt[n] + 1));  // +1 = self-loop
}

// exclusive scan of PADDED cnt -> row_ptr (degree padded to multiple of 4)
__global__ void scan1_kernel(const int* __restrict__ cnt, int* __restrict__ row_ptr,
                             int* __restrict__ bsum, int N) {
  __shared__ int sd[256];
  int tid = threadIdx.x, b = blockIdx.x;
  int i0 = b * 1024 + tid * 4;
  int v[4];
#pragma unroll
  for (int m = 0; m < 4; ++m) v[m] = (i0 + m < N) ? ((cnt[i0 + m] + 3) & ~3) : 0;
  int s = v[0] + v[1] + v[2] + v[3];
  sd[tid] = s;
  __syncthreads();
  for (int off = 1; off < 256; off <<= 1) {
    int t = (tid >= off) ? sd[tid - off] : 0;
    __syncthreads();
    sd[tid] += t;
    __syncthreads();
  }
  int run = sd[tid] - s;
#pragma unroll
  for (int m = 0; m < 4; ++m) {
    if (i0 + m < N) row_ptr[i0 + m] = run;
    run += v[m];
  }
  if (tid == 255) bsum[b] = sd[255];
}

__global__ void scan2_kernel(const int* __restrict__ bsum, int* __restrict__ bofs,
                             int* __restrict__ row_ptr, int NB, int N) {
  __shared__ int sd[128];
  int tid = threadIdx.x;
  int v = (tid < NB) ? bsum[tid] : 0;
  sd[tid] = v;
  __syncthreads();
  for (int off = 1; off < 128; off <<= 1) {
    int t = (tid >= off) ? sd[tid - off] : 0;
    __syncthreads();
    sd[tid] += t;
    __syncthreads();
  }
  if (tid < NB) bofs[tid] = sd[tid] - v;
  if (tid == 127) row_ptr[N] = sd[127];
}

__global__ void scan3_kernel(int* __restrict__ row_ptr, const int* __restrict__ bofs, int N) {
  int b = blockIdx.x;
  if (b == 0) return;
  int add = bofs[b];
  int i0 = b * 1024 + threadIdx.x * 4;
#pragma unroll
  for (int m = 0; m < 4; ++m)
    if (i0 + m < N) row_ptr[i0 + m] += add;
}

// edges[p] = {src, dinv[src] bits}
__global__ void fill_kernel(const int* __restrict__ src, const int* __restrict__ dst,
                            const int* __restrict__ row_ptr, int* __restrict__ cnt2,
                            const float* __restrict__ dinv,
                            int2* __restrict__ edges, int E) {
  int e = blockIdx.x * 256 + threadIdx.x;
  if (e >= E) return;
  int s = src[e], d = dst[e];
  int p = row_ptr[d] + atomicAdd(&cnt2[d], 1);
  edges[p] = make_int2(s, __float_as_int(dinv[s]));
}

// fill padded tail records with zero-weight self edges
__global__ void pad_kernel(const int* __restrict__ cnt, const int* __restrict__ row_ptr,
                           int2* __restrict__ edges, int N) {
  int n = blockIdx.x * 256 + threadIdx.x;
  if (n >= N) return;
  int a = row_ptr[n] + cnt[n];
  int b = row_ptr[n + 1];
  for (int p = a; p < b; ++p) edges[p] = make_int2(n, 0);
}

// ---------------- weight convert ----------------

__global__ void convert_w1(const float* __restrict__ W1, unsigned short* __restrict__ W1T) {
  int i = blockIdx.x * 256 + threadIdx.x;  // W1T[c][k], c<512, k<256
  if (i >= D_HID * D_IN) return;
  int c = i >> 8, k = i & 255;
  W1T[i] = f2bf(W1[k * D_HID + c]);
}

__global__ void convert_w2(const float* __restrict__ W2, unsigned short* __restrict__ W2T) {
  int i = blockIdx.x * 256 + threadIdx.x;  // W2T[n][k], n<48, k<512
  if (i >= D_OUT * D_HID) return;
  int n = i >> 9, k = i & 511;
  W2T[i] = f2bf(W2[k * D_OUT + n]);
}

// ---------------- fused MLP encoder (unchanged structure; h2 stride 64) ----------------

__global__ __launch_bounds__(256, 3) void encoder_kernel(
    const float* __restrict__ x, const float* __restrict__ b1,
    const float* __restrict__ b2,
    const unsigned short* __restrict__ W1T,   // [512][256] bf16
    const unsigned short* __restrict__ W2T,   // [48][512]  bf16
    __half* __restrict__ h2, int N) {
  __shared__ unsigned short sB[64][136];    // W1T tile: c(64) x k(128), pad 8
  __shared__ unsigned short sHid[128][72];  // m x hid-col(64), wave-private rows
  __shared__ unsigned short sW2[48][72];    // n(48) x hid-col(64)

  int tid = threadIdx.x;
  int w = tid >> 6, lane = tid & 63;
  int q = lane >> 4, l15 = lane & 15;
  int row0 = blockIdx.x * 128;
  int m0 = w * 16;

  bf16x8 axf[2][8];
#pragma unroll
  for (int mt = 0; mt < 2; ++mt) {
    int grow = row0 + mt * 64 + m0 + l15;
    bool rok = grow < N;
    const float* xr = x + (size_t)grow * D_IN;
#pragma unroll
    for (int jb = 0; jb < 8; ++jb) {
      float4 v0 = make_float4(0.f, 0.f, 0.f, 0.f), v1 = v0;
      if (rok) {
        v0 = *(const float4*)(xr + jb * 32 + q * 8);
        v1 = *(const float4*)(xr + jb * 32 + q * 8 + 4);
      }
      union { bf16x8 v; unsigned short s[8]; } u;
      u.s[0] = f2bf(v0.x); u.s[1] = f2bf(v0.y); u.s[2] = f2bf(v0.z); u.s[3] = f2bf(v0.w);
      u.s[4] = f2bf(v1.x); u.s[5] = f2bf(v1.y); u.s[6] = f2bf(v1.z); u.s[7] = f2bf(v1.w);
      axf[mt][jb] = u.v;
    }
  }

  f32x4 hacc[2][3];
#pragma unroll
  for (int mt = 0; mt < 2; ++mt)
#pragma unroll
    for (int t = 0; t < 3; ++t)
#pragma unroll
      for (int r = 0; r < 4; ++r) hacc[mt][t][r] = 0.f;

  for (int ct = 0; ct < 8; ++ct) {
    int c0 = ct * 64;
    f32x4 acc[2][4];
#pragma unroll
    for (int mt = 0; mt < 2; ++mt)
#pragma unroll
      for (int t = 0; t < 4; ++t)
#pragma unroll
        for (int r = 0; r < 4; ++r) acc[mt][t][r] = 0.f;

#pragma unroll
    for (int kh = 0; kh < 2; ++kh) {
      __syncthreads();
#pragma unroll
      for (int i = 0; i < 4; ++i) {
        int id = i * 256 + tid;
        int r = id >> 4, c = id & 15;
        *(uint4*)&sB[r][c * 8] =
            *(const uint4*)(W1T + (size_t)(c0 + r) * D_IN + kh * 128 + c * 8);
      }
      if (kh == 0) {
        int r = tid >> 3, c8 = tid & 7;
        *(uint4*)&sW2[r][c8 * 8] = *(const uint4*)(W2T + (size_t)r * D_HID + c0 + c8 * 8);
        int id = 256 + tid;
        if (id < 384) {
          int r2 = id >> 3, c2 = id & 7;
          *(uint4*)&sW2[r2][c2 * 8] = *(const uint4*)(W2T + (size_t)r2 * D_HID + c0 + c2 * 8);
        }
      }
      __syncthreads();
#pragma unroll
      for (int kb = 0; kb < 4; ++kb) {
#pragma unroll
        for (int tn = 0; tn < 4; ++tn) {
          bf16x8 b = *(const bf16x8*)&sB[tn * 16 + l15][kb * 32 + q * 8];
          acc[0][tn] = __builtin_amdgcn_mfma_f32_16x16x32_bf16(axf[0][kh * 4 + kb], b, acc[0][tn], 0, 0, 0);
          acc[1][tn] = __builtin_amdgcn_mfma_f32_16x16x32_bf16(axf[1][kh * 4 + kb], b, acc[1][tn], 0, 0, 0);
        }
      }
    }
#pragma unroll
    for (int mt = 0; mt < 2; ++mt)
#pragma unroll
      for (int tn = 0; tn < 4; ++tn) {
        int c = tn * 16 + l15;
        float bias = b1[c0 + c];
#pragma unroll
        for (int rg = 0; rg < 4; ++rg) {
          float v = acc[mt][tn][rg] + bias;
          v = v > 0.f ? v : 0.f;
          sHid[mt * 64 + m0 + q * 4 + rg][c] = f2bf(v);
        }
      }
#pragma unroll
    for (int kk = 0; kk < 2; ++kk) {
      bf16x8 a0 = *(const bf16x8*)&sHid[m0 + l15][kk * 32 + q * 8];
      bf16x8 a1 = *(const bf16x8*)&sHid[64 + m0 + l15][kk * 32 + q * 8];
#pragma unroll
      for (int tn = 0; tn < 3; ++tn) {
        bf16x8 b = *(const bf16x8*)&sW2[tn * 16 + l15][kk * 32 + q * 8];
        hacc[0][tn] = __builtin_amdgcn_mfma_f32_16x16x32_bf16(a0, b, hacc[0][tn], 0, 0, 0);
        hacc[1][tn] = __builtin_amdgcn_mfma_f32_16x16x32_bf16(a1, b, hacc[1][tn], 0, 0, 0);
      }
    }
  }
  // epilogue: h2 = f16(hacc + b2), padded cols 48..63 zeroed
#pragma unroll
  for (int mt = 0; mt < 2; ++mt) {
#pragma unroll
    for (int tn = 0; tn < 3; ++tn) {
      int c = tn * 16 + l15;
      float bias = b2[c];
#pragma unroll
      for (int rg = 0; rg < 4; ++rg) {
        int gr = row0 + mt * 64 + m0 + q * 4 + rg;
        if (gr < N) h2[(size_t)gr * HPAD + c] = __float2half(hacc[mt][tn][rg] + bias);
      }
    }
#pragma unroll
    for (int rg = 0; rg < 4; ++rg) {
      int gr = row0 + mt * 64 + m0 + q * 4 + rg;
      if (gr < N) h2[(size_t)gr * HPAD + 48 + l15] = __float2half(0.f);
    }
  }
}

// ---------------- APPNP propagation: 2 nodes/wave, 4 slots x 8 lanes ----------------
// lane = (half<<5)|(slot<<3)|s : half selects node, slot = edge within batch,
// s = 16-B feature chunk of the padded 128-B row. All 64 lanes active.
// Degrees padded to mult of 4 -> no tail; slot-fold via fixed ds_swizzle.

__global__ __launch_bounds__(256) void prop_kernel(
    const __half* __restrict__ cur, const __half* __restrict__ h2,
    const float* __restrict__ dinv, const int* __restrict__ row_ptr,
    const int2* __restrict__ edges, __half* __restrict__ nxt,
    float* __restrict__ outf, int N, int last) {
  int wid = (blockIdx.x * 256 + threadIdx.x) >> 6;
  int lane = threadIdx.x & 63;
  int half = lane >> 5;
  int slot = (lane >> 3) & 3;
  int s = lane & 7;
  int node = wid * 2 + half;
  bool nok = node < N;
  int p0 = 0, p1 = 0;
  if (nok) { int2 pp = *(const int2*)(row_ptr + node); p0 = pp.x; p1 = pp.y; }
  int d = p1 - p0;                          // padded degree (mult of 4)
  int dmax = max(d, __shfl_xor(d, 32));     // pair max
  int nb = dmax >> 2;

  float acc[8];
#pragma unroll
  for (int i = 0; i < 8; ++i) acc[i] = 0.f;

  int p = p0 + slot;
  int2 er = make_int2(0, 0);
  if (nb > 0) er = edges[p];
  for (int b = 0; b < nb; ++b) {
    float wgt = (p < p1) ? __int_as_float(er.y) : 0.f;
    int sn = er.x;
    int2 ern = er;
    if (b + 1 < nb) ern = edges[p + 4];     // prefetch (uniform branch)
    union { float4 f; __half2 h[4]; } u;
    u.f = *(const float4*)(cur + ((size_t)sn << 6) + s * 8);
#pragma unroll
    for (int i = 0; i < 4; ++i) {
      float2 f = __half22float2(u.h[i]);
      acc[2 * i]     += wgt * f.x;
      acc[2 * i + 1] += wgt * f.y;
    }
    er = ern; p += 4;
  }
  // fold the 4 slots (lane bits 3,4) via fixed-pattern swizzles
#pragma unroll
  for (int i = 0; i < 8; ++i) {
    acc[i] += __int_as_float(__builtin_amdgcn_ds_swizzle(__float_as_int(acc[i]), 0x201F)); // ^8
    acc[i] += __int_as_float(__builtin_amdgcn_ds_swizzle(__float_as_int(acc[i]), 0x401F)); // ^16
  }
  if ((lane & 24) != 0 || !nok) return;
  float di = dinv[node];
  size_t base = ((size_t)node << 6) + s * 8;
  union { float4 f; __half2 h[4]; } us, uh;
  us.f = *(const float4*)(cur + base);
  uh.f = *(const float4*)(h2 + base);
  float dii = di * di;
  float outv[8];
#pragma unroll
  for (int i = 0; i < 4; ++i) {
    float2 sf = __half22float2(us.h[i]);
    float2 hf = __half22float2(uh.h[i]);
    outv[2 * i]     = 0.9f * (di * acc[2 * i]     + dii * sf.x) + 0.1f * hf.x;
    outv[2 * i + 1] = 0.9f * (di * acc[2 * i + 1] + dii * sf.y) + 0.1f * hf.y;
  }
  if (last) {
    if (s < 6) {  // only the 48 real features
      float* op = outf + (size_t)node * D_OUT + s * 8;
      *(float4*)op       = make_float4(outv[0], outv[1], outv[2], outv[3]);
      *(float4*)(op + 4) = make_float4(outv[4], outv[5], outv[6], outv[7]);
    }
  } else {
    union { uint4 u4; __half2 h[4]; } o;
#pragma unroll
    for (int i = 0; i < 4; ++i) o.h[i] = __floats2half2_rn(outv[2 * i], outv[2 * i + 1]);
    *(uint4*)(nxt + base) = o.u4;
  }
}

// ---------------- launch ----------------

extern "C" void kernel_launch(void* const* d_in, const int* in_sizes, int n_in,
                              void* d_out, int out_size, void* d_ws, size_t ws_size,
                              hipStream_t stream) {
  (void)n_in; (void)out_size; (void)ws_size;
  const float* x  = (const float*)d_in[0];
  const int*   ei = (const int*)d_in[1];
  const float* W1 = (const float*)d_in[2];
  const float* b1 = (const float*)d_in[3];
  const float* W2 = (const float*)d_in[4];
  const float* b2 = (const float*)d_in[5];
  const int N = in_sizes[0] / D_IN;
  const int E = in_sizes[1] / 2;
  const int* e_src = ei;
  const int* e_dst = ei + E;

  char* ws = (char*)d_ws;
  size_t off = 0;
  auto take = [&](size_t bytes) -> char* {
    char* p = ws + off;
    off += (bytes + 511) & ~(size_t)511;
    return p;
  };
  int* cnt      = (int*)take((size_t)N * 4);
  int* cnt2     = (int*)take((size_t)N * 4);
  float* dinv   = (float*)take((size_t)N * 4);
  int* row_ptr  = (int*)take((size_t)(N + 1) * 4);
  int* bsum     = (int*)take(1024);
  int* bofs     = (int*)take(1024);
  int2* edges   = (int2*)take(((size_t)E + 4 * (size_t)N) * 8);  // padded CSR
  unsigned short* W1T = (unsigned short*)take((size_t)D_IN * D_HID * 2);
  unsigned short* W2T = (unsigned short*)take((size_t)D_HID * D_OUT * 2);
  __half* h2    = (__half*)take((size_t)N * HPAD * 2);
  __half* bufA  = (__half*)take((size_t)N * HPAD * 2);
  __half* bufB  = (__half*)d_out;   // 19.2 MB f32 out region holds 12.8 MB f16 buf;
                                    // only written before final f32 output
  float* outp   = (float*)d_out;

  int nb256 = (N + 255) / 256;
  int eb256 = (E + 255) / 256;
  int NB    = (N + 1023) / 1024;   // 98 <= 128 ok

  // graph build (padded CSR)
  zero2_kernel<<<nb256, 256, 0, stream>>>(cnt, cnt2, N);
  count_kernel<<<eb256, 256, 0, stream>>>(e_dst, cnt, E);
  dinv_kernel<<<nb256, 256, 0, stream>>>(cnt, dinv, N);
  scan1_kernel<<<NB, 256, 0, stream>>>(cnt, row_ptr, bsum, N);
  scan2_kernel<<<1, 128, 0, stream>>>(bsum, bofs, row_ptr, NB, N);
  scan3_kernel<<<NB, 256, 0, stream>>>(row_ptr, bofs, N);
  fill_kernel<<<eb256, 256, 0, stream>>>(e_src, e_dst, row_ptr, cnt2, dinv, edges, E);
  pad_kernel<<<nb256, 256, 0, stream>>>(cnt, row_ptr, edges, N);

  // encoder
  convert_w1<<<(D_IN * D_HID + 255) / 256, 256, 0, stream>>>(W1, W1T);
  convert_w2<<<(D_HID * D_OUT + 255) / 256, 256, 0, stream>>>(W2, W2T);
  encoder_kernel<<<(N + 127) / 128, 256, 0, stream>>>(x, b1, b2, W1T, W2T, h2, N);

  // APPNP: 10 iters; buffers h2 -> A -> B(d_out) -> A ... -> A -> f32 d_out
  int waves = (N + 1) / 2;
  int pblocks = (waves + 3) / 4;
  const __half* src = h2;
  __half* dst = bufA;
  for (int it = 1; it <= K_STEPS; ++it) {
    int last = (it == K_STEPS);
    prop_kernel<<<pblocks, 256, 0, stream>>>(src, h2, dinv, row_ptr, edges,
                                             dst, outp, N, last);
    src = dst;
    dst = (dst == bufA) ? bufB : bufA;
  }
}